// Round 4
// baseline (950.136 us; speedup 1.0000x reference)
//
#include <hip/hip_runtime.h>
#include <hip/hip_cooperative_groups.h>
#include <math.h>

namespace cg = cooperative_groups;

// Debiased Sinkhorn divergence (p=1, blur=0.01, scaling=0.5) fused into one
// cooperative kernel (grid.sync between eps iterations), with a multi-kernel
// fallback if the cooperative launch is rejected (return code checked!).
// B=2048 (NB hardcoded), K=128 runtime. State: x + 2x4 potentials ~ 72KB.

#define BLK 256
#define NB  2048

// ---- one softmin row-task: val = -eps*LSE_j( logw + (h_j - |xi - src_j|)/eps )
// pot: 0=ft(x rows, cols y, h=g) 1=gt(y,x,h=f) 2=faa(x,x,h=faa) 3=gbb(y,y,h=gbb)
// Returns val on ALL lanes (butterfly reductions).
__device__ __forceinline__ float softmin_task(int pot, int row,
        const float* __restrict__ x, const float* __restrict__ y,
        const float* __restrict__ cur, float se, float c0, float c1, int lane) {
    const float* xs  = (pot & 1) ? y : x;
    const float* src = ((pot ^ (pot >> 1)) & 1) ? x : y;
    const int hIdx   = (pot < 2) ? (1 - pot) : pot;
    const float4* h4 = (const float4*)(cur + hIdx * NB);
    const float4* s4 = (const float4*)src;
    const float xi   = xs[row];

    float s[32];
    #pragma unroll
    for (int k = 0; k < 8; ++k) {
        float4 hv = h4[(k << 6) + lane];
        float4 sv = s4[(k << 6) + lane];
        s[4 * k + 0] = (hv.x - fabsf(xi - sv.x)) * se;
        s[4 * k + 1] = (hv.y - fabsf(xi - sv.y)) * se;
        s[4 * k + 2] = (hv.z - fabsf(xi - sv.z)) * se;
        s[4 * k + 3] = (hv.w - fabsf(xi - sv.w)) * se;
    }
    float m0 = s[0], m1 = s[1], m2 = s[2], m3 = s[3];
    #pragma unroll
    for (int i = 4; i < 32; i += 4) {
        m0 = fmaxf(m0, s[i + 0]); m1 = fmaxf(m1, s[i + 1]);
        m2 = fmaxf(m2, s[i + 2]); m3 = fmaxf(m3, s[i + 3]);
    }
    float m = fmaxf(fmaxf(m0, m1), fmaxf(m2, m3));
    #pragma unroll
    for (int off = 32; off; off >>= 1) m = fmaxf(m, __shfl_xor(m, off));

    float a0 = 0.f, a1 = 0.f, a2 = 0.f, a3 = 0.f;
    #pragma unroll
    for (int i = 0; i < 32; i += 4) {
        a0 += exp2f(s[i + 0] - m); a1 += exp2f(s[i + 1] - m);
        a2 += exp2f(s[i + 2] - m); a3 += exp2f(s[i + 3] - m);
    }
    float acc = (a0 + a1) + (a2 + a3);
    #pragma unroll
    for (int off = 32; off; off >>= 1) acc += __shfl_xor(acc, off);

    return c0 + c1 * (m + __log2f(acc));
}

__device__ __forceinline__ void prep_work(const float* __restrict__ pred,
        float* __restrict__ x, float* __restrict__ s0,
        int K, int gid, int gsz, int w, int nw, int lane) {
    for (int i = gid; i < 4 * NB; i += gsz) s0[i] = 0.f;
    for (int row = w; row < NB; row += nw) {
        const float* pr = pred + (size_t)row * K;
        float s2 = 0.f, wsum = 0.f;
        for (int k = lane; k < K; k += 64) {
            float v = fmaxf(pr[k], 0.f);
            s2   += v * v;
            wsum += v * (float)k;
        }
        #pragma unroll
        for (int off = 32; off; off >>= 1) {
            s2   += __shfl_xor(s2, off);
            wsum += __shfl_xor(wsum, off);
        }
        if (lane == 0) x[row] = wsum / fmaxf(sqrtf(s2), 1e-12f);
    }
}

// ================= cooperative (preferred) =================
__global__ __launch_bounds__(BLK, 4)
void sink_coop(const float* __restrict__ pred, const float* __restrict__ target,
               float* __restrict__ ws, float* __restrict__ out, int K) {
    cg::grid_group grid = cg::this_grid();
    float* x  = ws;
    float* s0 = ws + NB;
    float* s1 = ws + 5 * NB;

    const int tid  = threadIdx.x;
    const int lane = tid & 63;
    const int w    = blockIdx.x * (BLK / 64) + (tid >> 6);
    const int nw   = gridDim.x * (BLK / 64);
    const int gid  = blockIdx.x * BLK + tid;
    const int gsz  = gridDim.x * BLK;

    prep_work(pred, x, s0, K, gid, gsz, w, nw, lane);
    grid.sync();

    int nH = 0;
    { double e = (double)K; while (e > 0.01) { nH++; e *= 0.5; } }
    const int nTot = nH + 2;
    const float logB = logf((float)NB);

    double ecur = (double)K;
    for (int it = 0; it < nTot; ++it) {
        const float eps = (it < nH) ? (float)ecur : 0.01f;
        const int avg = (it < nTot - 1);
        const float* cur = (it & 1) ? s1 : s0;
        float*       nxt = (it & 1) ? s0 : s1;
        const float se = 1.4426950408889634f / eps;            // log2(e)/eps
        const float c0 = eps * logB;                           // -eps*logw
        const float c1 = -eps * 0.69314718055994531f;          // -eps*ln2

        for (int t = w; t < 4 * NB; t += nw) {
            const int pot = t >> 11;           // NB == 2048
            const int row = t & (NB - 1);
            float val = softmin_task(pot, row, x, target, cur, se, c0, c1, lane);
            if (lane == 0) nxt[t] = avg ? 0.5f * (cur[t] + val) : val;
        }
        grid.sync();
        ecur *= 0.5;
    }

    if (blockIdx.x == 0) {
        const float* fin = ((nTot - 1) & 1) ? s0 : s1;
        float p = 0.f;
        for (int i = tid; i < NB; i += BLK)
            p += (fin[i] - fin[2 * NB + i]) + (fin[NB + i] - fin[3 * NB + i]);
        #pragma unroll
        for (int off = 32; off; off >>= 1) p += __shfl_xor(p, off);
        __shared__ float sp[BLK / 64];
        if (lane == 0) sp[tid >> 6] = p;
        __syncthreads();
        if (tid == 0) {
            float t2 = 0.f;
            #pragma unroll
            for (int i = 0; i < BLK / 64; ++i) t2 += sp[i];
            out[0] = t2 / (float)NB;
        }
    }
}

// ================= non-cooperative fallback =================
__global__ __launch_bounds__(BLK)
void prep_fb(const float* __restrict__ pred, float* __restrict__ x,
             float* __restrict__ s0, int K) {
    const int tid = threadIdx.x, lane = tid & 63;
    const int w   = blockIdx.x * (BLK / 64) + (tid >> 6);
    const int nw  = gridDim.x * (BLK / 64);
    const int gid = blockIdx.x * BLK + tid;
    const int gsz = gridDim.x * BLK;
    prep_work(pred, x, s0, K, gid, gsz, w, nw, lane);
}

__global__ __launch_bounds__(BLK)
void iter_fb(const float* __restrict__ x, const float* __restrict__ y,
             const float* __restrict__ cur, float* __restrict__ nxt,
             float se, float c0, float c1, int avg) {
    const int tid = threadIdx.x, lane = tid & 63;
    const int w   = blockIdx.x * (BLK / 64) + (tid >> 6);
    const int nw  = gridDim.x * (BLK / 64);
    for (int t = w; t < 4 * NB; t += nw) {
        const int pot = t >> 11;
        const int row = t & (NB - 1);
        float val = softmin_task(pot, row, x, y, cur, se, c0, c1, lane);
        if (lane == 0) nxt[t] = avg ? 0.5f * (cur[t] + val) : val;
    }
}

__global__ __launch_bounds__(BLK)
void final_fb(const float* __restrict__ fin, float* __restrict__ out) {
    const int tid = threadIdx.x, lane = tid & 63;
    float p = 0.f;
    for (int i = tid; i < NB; i += BLK)
        p += (fin[i] - fin[2 * NB + i]) + (fin[NB + i] - fin[3 * NB + i]);
    #pragma unroll
    for (int off = 32; off; off >>= 1) p += __shfl_xor(p, off);
    __shared__ float sp[BLK / 64];
    if (lane == 0) sp[tid >> 6] = p;
    __syncthreads();
    if (tid == 0) {
        float t2 = 0.f;
        #pragma unroll
        for (int i = 0; i < BLK / 64; ++i) t2 += sp[i];
        out[0] = t2 / (float)NB;
    }
}

extern "C" void kernel_launch(void* const* d_in, const int* in_sizes, int n_in,
                              void* d_out, int out_size, void* d_ws, size_t ws_size,
                              hipStream_t stream) {
    const float* pred   = (const float*)d_in[0];
    const float* target = (const float*)d_in[1];
    const int B = in_sizes[1];
    const int K = in_sizes[0] / B;        // 128 == diameter
    float* ws  = (float*)d_ws;
    float* out = (float*)d_out;

    // ---- try cooperative, grid sized from actual occupancy (capture-safe query)
    int perCU = 0;
    hipError_t oe = hipOccupancyMaxActiveBlocksPerMultiprocessor(
        &perCU, (const void*)sink_coop, BLK, 0);
    bool done = false;
    if (oe == hipSuccess && perCU > 0) {
        int nblk = perCU * 256;           // 256 CUs on MI355X
        if (nblk > 1024) nblk = 1024;
        void* args[] = { (void*)&pred, (void*)&target, (void*)&ws, (void*)&out,
                         (void*)&K };
        hipError_t le = hipLaunchCooperativeKernel((const void*)sink_coop,
                                                   dim3(nblk), dim3(BLK), args,
                                                   0, stream);
        done = (le == hipSuccess);
        if (!done) (void)hipGetLastError();   // clear error state
    } else {
        (void)hipGetLastError();
    }

    // ---- fallback: serial multi-kernel (known-good structure)
    if (!done) {
        float* x  = ws;
        float* s0 = ws + NB;
        float* s1 = ws + 5 * NB;

        prep_fb<<<dim3(512), dim3(BLK), 0, stream>>>(pred, x, s0, K);

        double epsl[64]; int ne = 0;
        double e = (double)K;
        while (e > 0.01 && ne < 62) { epsl[ne++] = e; e *= 0.5; }
        epsl[ne++] = 0.01;                 // ne = 15 averaged; +1 extrapolation

        const float logB = logf((float)NB);
        int cur = 0;
        for (int i = 0; i <= ne; ++i) {
            const float eps = (i < ne) ? (float)epsl[i] : 0.01f;
            const int avg = (i < ne);
            const float* cb = cur ? s1 : s0;
            float*       nb = cur ? s0 : s1;
            iter_fb<<<dim3(2048), dim3(BLK), 0, stream>>>(
                x, target, cb, nb,
                1.4426950408889634f / eps, eps * logB,
                -eps * 0.69314718055994531f, avg);
            cur ^= 1;
        }
        final_fb<<<dim3(1), dim3(BLK), 0, stream>>>(cur ? s1 : s0, out);
    }
}